// Round 1
// baseline (47.910 us; speedup 1.0000x reference)
//
#include <hip/hip_runtime.h>
#include <hip/hip_bf16.h>

// out[b][d][n] = E[n][d], b<32, d<128, n<16384. Pure transpose+broadcast.
// Write-BW bound: 268 MB fp32 stores. LDS tile-transpose so stores are
// coalesced float4 along n.

#define NN 16384
#define DD 128
#define NT 64     // n per block tile
#define BT 4      // batches per block
#define NBATCH 32

__global__ __launch_bounds__(256) void tree_embed_bcast_kernel(
    const float* __restrict__ E, float* __restrict__ out) {
    // +1 pad on inner dim to break power-of-2 bank stride
    __shared__ float lds[DD][NT + 1];  // 128 x 65 floats = 33,280 B

    const int n0 = blockIdx.x * NT;
    const int b0 = blockIdx.y * BT;
    const int tid = threadIdx.x;

    // ---- Phase 1: load E[n0..n0+63][0..127] (coalesced float4 along d),
    //      store transposed into LDS.
    {
        const int c = tid & 31;   // float4 column: d = 4*c .. 4*c+3
        const int r = tid >> 5;   // row 0..7 within group
        #pragma unroll
        for (int it = 0; it < NT / 8; ++it) {
            const int n = r + it * 8;  // 0..63
            const float4 v = *reinterpret_cast<const float4*>(
                &E[(size_t)(n0 + n) * DD + (c << 2)]);
            lds[(c << 2) + 0][n] = v.x;
            lds[(c << 2) + 1][n] = v.y;
            lds[(c << 2) + 2][n] = v.z;
            lds[(c << 2) + 3][n] = v.w;
        }
    }
    __syncthreads();

    // ---- Phase 2: write out[b][d][n0..n0+63] for b in [b0, b0+BT),
    //      all d. Each (b,d) row = 16 float4; 256 threads = 16 rows/iter.
    const int j = tid & 15;        // float4 slot within row (n_local = 4*j)
    const int row0 = tid >> 4;     // 0..15
    #pragma unroll 4
    for (int it = 0; it < (BT * DD) / 16; ++it) {   // 32 iters
        const int row = row0 + it * 16;             // 0..511
        const int d = row & (DD - 1);
        const int b = b0 + (row >> 7);
        float4 v;
        v.x = lds[d][(j << 2) + 0];
        v.y = lds[d][(j << 2) + 1];
        v.z = lds[d][(j << 2) + 2];
        v.w = lds[d][(j << 2) + 3];
        const size_t oidx = (((size_t)b * DD + d) * NN) + n0 + (j << 2);
        *reinterpret_cast<float4*>(&out[oidx]) = v;
    }
}

extern "C" void kernel_launch(void* const* d_in, const int* in_sizes, int n_in,
                              void* d_out, int out_size, void* d_ws, size_t ws_size,
                              hipStream_t stream) {
    const float* E = (const float*)d_in[0];   // embed_node [16384,128]
    float* out = (float*)d_out;               // [32,128,16384,1]
    dim3 grid(NN / NT, NBATCH / BT);
    dim3 block(256);
    hipLaunchKernelGGL(tree_embed_bcast_kernel, grid, block, 0, stream, E, out);
}